// Round 2
// baseline (13030.870 us; speedup 1.0000x reference)
//
#include <hip/hip_runtime.h>
#include <math.h>

#define D_MODEL 388
#define N_BLOCKS 5
#define D_INNER 776
#define D_STATE 16
#define D_CONV 4
#define DT_RANK 25
#define SEQ 145
#define NUM_CLASSES 3
#define BATCH 256
#define XPROJ_OUT (DT_RANK + 2 * D_STATE)  // 57

// ---------------- wave reduction ----------------
__device__ inline float wave_sum(float v) {
#pragma unroll
    for (int off = 32; off; off >>= 1) v += __shfl_xor(v, off);
    return v;
}

__device__ inline float silu(float x) { return x / (1.f + __expf(-x)); }

// ---------------- LayerNorm: one wave per token (in-place capable) --------
__global__ __launch_bounds__(64) void ln_kernel(const float* __restrict__ x,
                                                const float* __restrict__ g,
                                                const float* __restrict__ b,
                                                float* __restrict__ out) {
    int tok = blockIdx.x;
    int lane = threadIdx.x;
    const float* xr = x + (size_t)tok * D_MODEL;
    float* orow = out + (size_t)tok * D_MODEL;
    float vals[7];
    float s = 0.f;
#pragma unroll
    for (int i = 0; i < 7; i++) {
        int idx = lane + i * 64;
        float v = (idx < D_MODEL) ? xr[idx] : 0.f;
        vals[i] = v;
        s += v;
    }
    s = wave_sum(s);
    float mu = s * (1.f / D_MODEL);
    float vs = 0.f;
#pragma unroll
    for (int i = 0; i < 7; i++) {
        int idx = lane + i * 64;
        if (idx < D_MODEL) {
            float d = vals[i] - mu;
            vs += d * d;
        }
    }
    vs = wave_sum(vs);
    float rstd = rsqrtf(vs * (1.f / D_MODEL) + 1e-5f);
#pragma unroll
    for (int i = 0; i < 7; i++) {
        int idx = lane + i * 64;
        if (idx < D_MODEL) orow[idx] = (vals[i] - mu) * rstd * g[idx] + b[idx];
    }
}

// ---------------- generic fp32 GEMM: C[m][n] = sum_k A[m][k] * W[n][k] ----
#define EP_PLAIN 0
#define EP_SPLIT 1   // n<776 -> C raw ; n>=776 -> C2 silu'd

template <int MODE>
__global__ __launch_bounds__(256) void gemm_kernel(
    const float* __restrict__ A, int lda, const float* __restrict__ W, int ldw,
    float* __restrict__ C, int ldc, float* __restrict__ C2,
    int M, int N, int K) {
    __shared__ float As[16][68];
    __shared__ float Ws[16][68];
    int tid = threadIdx.x;
    int tx = tid & 15, ty = tid >> 4;
    int mstart = blockIdx.x * 64;
    int nstart = blockIdx.y * 64;
    float acc[4][4] = {};
    int lr = tid >> 2;         // 0..63
    int lk = (tid & 3) * 4;    // 0,4,8,12
    for (int k0 = 0; k0 < K; k0 += 16) {
        int m = mstart + lr;
        int n = nstart + lr;
#pragma unroll
        for (int i = 0; i < 4; i++) {
            int k = k0 + lk + i;
            As[lk + i][lr] = (m < M && k < K) ? A[(size_t)m * lda + k] : 0.f;
            Ws[lk + i][lr] = (n < N && k < K) ? W[(size_t)n * ldw + k] : 0.f;
        }
        __syncthreads();
#pragma unroll
        for (int kk = 0; kk < 16; kk++) {
            float a[4], w[4];
#pragma unroll
            for (int i = 0; i < 4; i++) a[i] = As[kk][ty * 4 + i];
#pragma unroll
            for (int j = 0; j < 4; j++) w[j] = Ws[kk][tx * 4 + j];
#pragma unroll
            for (int i = 0; i < 4; i++)
#pragma unroll
                for (int j = 0; j < 4; j++)
                    acc[i][j] = fmaf(a[i], w[j], acc[i][j]);
        }
        __syncthreads();
    }
#pragma unroll
    for (int i = 0; i < 4; i++) {
        int m = mstart + ty * 4 + i;
        if (m >= M) continue;
#pragma unroll
        for (int j = 0; j < 4; j++) {
            int n = nstart + tx * 4 + j;
            if (n >= N) continue;
            float v = acc[i][j];
            if (MODE == EP_PLAIN) {
                C[(size_t)m * ldc + n] = v;
            } else {  // EP_SPLIT
                if (n < D_INNER) C[(size_t)m * D_INNER + n] = v;
                else C2[(size_t)m * D_INNER + (n - D_INNER)] = silu(v);
            }
        }
    }
}

// ------- causal depthwise conv (k=4) + bias + silu, IN PLACE over x -------
__global__ __launch_bounds__(256) void conv_silu_kernel(
    float* __restrict__ x, const float* __restrict__ w,
    const float* __restrict__ cb) {
    int d = blockIdx.x * 256 + threadIdx.x;
    if (d >= D_INNER) return;
    int b = blockIdx.y;
    size_t base = (size_t)b * SEQ * D_INNER + d;
    float w0 = w[d * 4 + 0], w1 = w[d * 4 + 1], w2 = w[d * 4 + 2], w3 = w[d * 4 + 3];
    float bias = cb[d];
    // descending t: writes at t never alias future reads (which are at <= t-3)
    float x0 = x[base + (size_t)(SEQ - 1) * D_INNER];   // x[t]
    float x1 = x[base + (size_t)(SEQ - 2) * D_INNER];   // x[t-1]
    float x2 = x[base + (size_t)(SEQ - 3) * D_INNER];   // x[t-2]
    for (int t = SEQ - 1; t >= 0; --t) {
        float x3 = (t - 3 >= 0) ? x[base + (size_t)(t - 3) * D_INNER] : 0.f;  // x[t-3]
        float acc = bias;
        acc = fmaf(w3, x0, acc);
        acc = fmaf(w2, x1, acc);
        acc = fmaf(w1, x2, acc);
        acc = fmaf(w0, x3, acc);
        x[base + (size_t)t * D_INNER] = silu(acc);
        x0 = x1; x1 = x2; x2 = x3;
    }
}

// ------- selective scan, fused dt_proj+softplus, *silu(z), y in place -----
__global__ __launch_bounds__(64) void scan_kernel(
    float* __restrict__ u_y,                 // in: u (conv'd x); out: y
    const float* __restrict__ dbl,           // (b, t, 57)
    const float* __restrict__ zs,            // silu(z) already applied
    const float* __restrict__ dt_w,          // (776, 25)
    const float* __restrict__ dt_b,          // (776,)
    const float* __restrict__ A_log,         // (776, 16)
    const float* __restrict__ Dp) {          // (776,)
    int b = blockIdx.y;
    int d = blockIdx.x * 64 + threadIdx.x;
    int lane = threadIdx.x;
    __shared__ float row[XPROJ_OUT];
    bool active = d < D_INNER;
    float A2[D_STATE], h[D_STATE], wdt[DT_RANK];
    float Dd = 0.f, dtb = 0.f;
    if (active) {
#pragma unroll
        for (int n = 0; n < D_STATE; n++) {
            A2[n] = -__expf(A_log[d * D_STATE + n]) * 1.44269504088896341f;
            h[n] = 0.f;
        }
#pragma unroll
        for (int r = 0; r < DT_RANK; r++) wdt[r] = dt_w[d * DT_RANK + r];
        Dd = Dp[d];
        dtb = dt_b[d];
    }
    size_t base = (size_t)b * SEQ * D_INNER + d;
    size_t dblbase = (size_t)b * SEQ * XPROJ_OUT;
    for (int t = 0; t < SEQ; t++) {
        if (lane < XPROJ_OUT) row[lane] = dbl[dblbase + (size_t)t * XPROJ_OUT + lane];
        __syncthreads();
        if (active) {
            float dtv = dtb;
#pragma unroll
            for (int r = 0; r < DT_RANK; r++) dtv = fmaf(wdt[r], row[r], dtv);
            // softplus (stable)
            dtv = fmaxf(dtv, 0.f) + log1pf(__expf(-fabsf(dtv)));
            size_t off = base + (size_t)t * D_INNER;
            float u_t = u_y[off];
            float du = dtv * u_t;
            float acc = 0.f;
#pragma unroll
            for (int n = 0; n < D_STATE; n++) {
                float dA = exp2f(dtv * A2[n]);
                h[n] = fmaf(dA, h[n], du * row[DT_RANK + n]);
                acc = fmaf(h[n], row[DT_RANK + D_STATE + n], acc);
            }
            acc = fmaf(u_t, Dd, acc);
            u_y[off] = acc * zs[off];
        }
        __syncthreads();
    }
}

// ---------------- classifier + softmax ----------------
__global__ __launch_bounds__(256) void cls_kernel(const float* __restrict__ xf,
                                                  const float* __restrict__ w,
                                                  const float* __restrict__ bias,
                                                  float* __restrict__ out) {
    const int F = SEQ * D_MODEL;  // 56260
    int b = blockIdx.x;
    int tid = threadIdx.x;
    const float* xr = xf + (size_t)b * F;
    float a0 = 0.f, a1 = 0.f, a2 = 0.f;
    for (int j = tid; j < F; j += 256) {
        float v = xr[j];
        a0 = fmaf(v, w[j], a0);
        a1 = fmaf(v, w[F + j], a1);
        a2 = fmaf(v, w[2 * F + j], a2);
    }
    a0 = wave_sum(a0);
    a1 = wave_sum(a1);
    a2 = wave_sum(a2);
    __shared__ float s[3][4];
    int wv = tid >> 6;
    if ((tid & 63) == 0) { s[0][wv] = a0; s[1][wv] = a1; s[2][wv] = a2; }
    __syncthreads();
    if (tid == 0) {
        float l0 = s[0][0] + s[0][1] + s[0][2] + s[0][3] + bias[0];
        float l1 = s[1][0] + s[1][1] + s[1][2] + s[1][3] + bias[1];
        float l2 = s[2][0] + s[2][1] + s[2][2] + s[2][3] + bias[2];
        float mx = fmaxf(l0, fmaxf(l1, l2));
        float e0 = expf(l0 - mx), e1 = expf(l1 - mx), e2 = expf(l2 - mx);
        float inv = 1.f / (e0 + e1 + e2);
        out[b * 3 + 0] = e0 * inv;
        out[b * 3 + 1] = e1 * inv;
        out[b * 3 + 2] = e2 * inv;
    }
}

extern "C" void kernel_launch(void* const* d_in, const int* in_sizes, int n_in,
                              void* d_out, int out_size, void* d_ws, size_t ws_size,
                              hipStream_t stream) {
    const float* x_in   = (const float*)d_in[0];
    const float* ln_g   = (const float*)d_in[1];
    const float* ln_b   = (const float*)d_in[2];
    const float* in_w   = (const float*)d_in[3];
    const float* conv_w = (const float*)d_in[4];
    const float* conv_b = (const float*)d_in[5];
    const float* xp_w   = (const float*)d_in[6];
    const float* dt_w   = (const float*)d_in[7];
    const float* dt_b   = (const float*)d_in[8];
    const float* A_log  = (const float*)d_in[9];
    const float* Dvec   = (const float*)d_in[10];
    const float* out_w  = (const float*)d_in[11];
    const float* cls_w  = (const float*)d_in[12];
    const float* cls_b  = (const float*)d_in[13];
    float* outp = (float*)d_out;
    float* ws = (float*)d_ws;

    // ---- choose batch chunk CB so the workspace fits ws_size ----
    int CB = BATCH;
    while (CB > 1) {
        size_t T = (size_t)CB * SEQ;
        size_t need = (T * D_MODEL + 2 * T * D_INNER + T * XPROJ_OUT) * sizeof(float);
        if (need <= ws_size) break;
        CB >>= 1;
    }
    const size_t T = (size_t)CB * SEQ;  // tokens per chunk

    float* x_cur = ws;                  // (T, 388)  LN'd in place; out_proj dest
    float* xc    = x_cur + T * D_MODEL; // (T, 776)  x half -> conv'd -> y
    float* zb    = xc + T * D_INNER;    // (T, 776)  silu(z)
    float* dbl   = zb + T * D_INNER;    // (T, 57)

    const int mblocks = (int)((T + 63) / 64);

    for (int c0 = 0; c0 < BATCH; c0 += CB) {
        for (int blk = 0; blk < N_BLOCKS; blk++) {
            const float* xsrc = (blk == 0) ? (x_in + (size_t)c0 * SEQ * D_MODEL) : x_cur;
            // 1. LayerNorm (in place for blk>0)
            ln_kernel<<<(int)T, 64, 0, stream>>>(xsrc, ln_g + blk * D_MODEL,
                                                 ln_b + blk * D_MODEL, x_cur);
            // 2. in_proj -> xc (raw), zb (silu'd)   M=T, N=1552, K=388
            {
                dim3 g(mblocks, (2 * D_INNER + 63) / 64);
                gemm_kernel<EP_SPLIT><<<g, 256, 0, stream>>>(
                    x_cur, D_MODEL, in_w + (size_t)blk * 2 * D_INNER * D_MODEL, D_MODEL,
                    xc, 0, zb, (int)T, 2 * D_INNER, D_MODEL);
            }
            // 3. causal conv + silu, in place on xc
            {
                dim3 g((D_INNER + 255) / 256, CB);
                conv_silu_kernel<<<g, 256, 0, stream>>>(
                    xc, conv_w + (size_t)blk * D_INNER * D_CONV,
                    conv_b + (size_t)blk * D_INNER);
            }
            // 4. x_proj -> dbl   M=T, N=57, K=776
            {
                dim3 g(mblocks, 1);
                gemm_kernel<EP_PLAIN><<<g, 256, 0, stream>>>(
                    xc, D_INNER, xp_w + (size_t)blk * XPROJ_OUT * D_INNER, D_INNER,
                    dbl, XPROJ_OUT, nullptr, (int)T, XPROJ_OUT, D_INNER);
            }
            // 5. scan (fused dt_proj+softplus, +u*D, *silu(z)), y over xc
            {
                dim3 g((D_INNER + 63) / 64, CB);
                scan_kernel<<<g, 64, 0, stream>>>(
                    xc, dbl, zb,
                    dt_w + (size_t)blk * D_INNER * DT_RANK,
                    dt_b + (size_t)blk * D_INNER,
                    A_log + (size_t)blk * D_INNER * D_STATE,
                    Dvec + (size_t)blk * D_INNER);
            }
            // 6. out_proj -> x_cur   M=T, N=388, K=776
            {
                dim3 g(mblocks, (D_MODEL + 63) / 64);
                gemm_kernel<EP_PLAIN><<<g, 256, 0, stream>>>(
                    xc, D_INNER, out_w + (size_t)blk * D_MODEL * D_INNER, D_INNER,
                    x_cur, D_MODEL, nullptr, (int)T, D_MODEL, D_INNER);
            }
        }
        // 7. classifier + softmax for this chunk
        cls_kernel<<<CB, 256, 0, stream>>>(x_cur, cls_w, cls_b, outp + (size_t)c0 * 3);
    }
}

// Round 3
// 4865.628 us; speedup vs baseline: 2.6781x; 2.6781x over previous
//
#include <hip/hip_runtime.h>
#include <math.h>

#define D_MODEL 388
#define N_BLOCKS 5
#define D_INNER 776
#define D_STATE 16
#define D_CONV 4
#define DT_RANK 25
#define SEQ 145
#define NUM_CLASSES 3
#define BATCH 256
#define XPROJ_OUT (DT_RANK + 2 * D_STATE)  // 57

// padded dims for MFMA (K multiple of 32, N multiple of tile)
#define KP_IN 416     // 388 -> 13*32
#define KP_DI 800     // 776 -> 25*32
#define NP_IN 1664    // 1552 -> 13*128
#define NP_XP 128     // 57 -> 128
#define NP_OUT 512    // 388 -> 4*128

typedef unsigned short ushort_t;
typedef short s16x8 __attribute__((ext_vector_type(8)));
typedef float f32x4 __attribute__((ext_vector_type(4)));

__device__ inline float wave_sum(float v) {
#pragma unroll
    for (int off = 32; off; off >>= 1) v += __shfl_xor(v, off);
    return v;
}
__device__ inline float silu(float x) { return x / (1.f + __expf(-x)); }
__device__ inline ushort_t f2bf(float f) {
    unsigned u = __builtin_bit_cast(unsigned, f);
    u = u + 0x7fffu + ((u >> 16) & 1u);
    return (ushort_t)(u >> 16);
}
__device__ inline float bf2f(ushort_t h) {
    unsigned u = ((unsigned)h) << 16;
    return __builtin_bit_cast(float, u);
}

// ---------- weight pad+convert fp32 -> bf16 (zero-padded) ----------
__global__ __launch_bounds__(256) void padcvt_kernel(const float* __restrict__ src,
                                                     ushort_t* __restrict__ dst,
                                                     int Ns, int Ks, int Np, int Kp,
                                                     int nblk) {
    int idx = blockIdx.x * 256 + threadIdx.x;
    int total = nblk * Np * Kp;
    if (idx >= total) return;
    int k = idx % Kp;
    int rest = idx / Kp;
    int n = rest % Np;
    int blk = rest / Np;
    float v = (n < Ns && k < Ks) ? src[((size_t)blk * Ns + n) * Ks + k] : 0.f;
    dst[idx] = f2bf(v);
}

// ---------- LayerNorm: one wave per token -> bf16 out (stride KP_IN) ------
__global__ __launch_bounds__(64) void ln_kernel(const float* __restrict__ x,
                                                const float* __restrict__ g,
                                                const float* __restrict__ b,
                                                ushort_t* __restrict__ out) {
    int tok = blockIdx.x;
    int lane = threadIdx.x;
    const float* xr = x + (size_t)tok * D_MODEL;
    ushort_t* orow = out + (size_t)tok * KP_IN;
    float vals[7];
    float s = 0.f;
#pragma unroll
    for (int i = 0; i < 7; i++) {
        int idx = lane + i * 64;
        float v = (idx < D_MODEL) ? xr[idx] : 0.f;
        vals[i] = v;
        s += v;
    }
    s = wave_sum(s);
    float mu = s * (1.f / D_MODEL);
    float vs = 0.f;
#pragma unroll
    for (int i = 0; i < 7; i++) {
        int idx = lane + i * 64;
        if (idx < D_MODEL) {
            float d = vals[i] - mu;
            vs += d * d;
        }
    }
    vs = wave_sum(vs);
    float rstd = rsqrtf(vs * (1.f / D_MODEL) + 1e-5f);
#pragma unroll
    for (int i = 0; i < 7; i++) {
        int idx = lane + i * 64;
        if (idx < D_MODEL) orow[idx] = f2bf((vals[i] - mu) * rstd * g[idx] + b[idx]);
    }
}

// ---------- MFMA bf16 GEMM: C[m][n] = sum_k A[m,k] W[n,k] ----------
// MODE 0: in_proj  (KP=416): n<776 -> xc bf16 ; 776<=n<1552 -> zs=silu bf16
// MODE 1: x_proj   (KP=800): n<57  -> dbl fp32 (ldc 57)
// MODE 2: out_proj (KP=800): n<388 -> x_cur fp32 (ldc 388)
template <int MODE>
__global__ __launch_bounds__(256) void mfma_gemm(const ushort_t* __restrict__ A,
                                                 const ushort_t* __restrict__ W,
                                                 float* __restrict__ fout,
                                                 ushort_t* __restrict__ bout1,
                                                 ushort_t* __restrict__ bout2,
                                                 int M) {
    constexpr int KP = (MODE == 0) ? KP_IN : KP_DI;
    __shared__ ushort_t As[128 * 40];
    __shared__ ushort_t Ws[128 * 40];
    int tid = threadIdx.x;
    int lane = tid & 63;
    int wave = tid >> 6;
    int wm = wave >> 1, wn = wave & 1;
    int mstart = blockIdx.x * 128;
    int nstart = blockIdx.y * 128;

    f32x4 acc[4][4];
#pragma unroll
    for (int i = 0; i < 4; i++)
#pragma unroll
        for (int j = 0; j < 4; j++) acc[i][j] = {0.f, 0.f, 0.f, 0.f};

    for (int k0 = 0; k0 < KP; k0 += 32) {
#pragma unroll
        for (int i = 0; i < 2; i++) {
            int idx = tid + i * 256;
            int r = idx >> 2;
            int c = (idx & 3) * 8;
            int ra = mstart + r;
            ra = (ra < M) ? ra : (M - 1);
            *(s16x8*)&As[r * 40 + c] = *(const s16x8*)&A[(size_t)ra * KP + k0 + c];
            *(s16x8*)&Ws[r * 40 + c] = *(const s16x8*)&W[(size_t)(nstart + r) * KP + k0 + c];
        }
        __syncthreads();
        s16x8 af[4], bfr[4];
        int koff = (lane >> 4) * 8;
        int rlo = lane & 15;
#pragma unroll
        for (int t = 0; t < 4; t++) {
            af[t] = *(s16x8*)&As[(wm * 64 + t * 16 + rlo) * 40 + koff];
            bfr[t] = *(s16x8*)&Ws[(wn * 64 + t * 16 + rlo) * 40 + koff];
        }
#pragma unroll
        for (int mt = 0; mt < 4; mt++)
#pragma unroll
            for (int nt = 0; nt < 4; nt++)
                acc[mt][nt] = __builtin_amdgcn_mfma_f32_16x16x32_bf16(
                    af[mt], bfr[nt], acc[mt][nt], 0, 0, 0);
        __syncthreads();
    }

    int col = lane & 15;
    int rowb = (lane >> 4) * 4;
#pragma unroll
    for (int mt = 0; mt < 4; mt++) {
#pragma unroll
        for (int nt = 0; nt < 4; nt++) {
            f32x4 v = acc[mt][nt];
            int n = nstart + wn * 64 + nt * 16 + col;
#pragma unroll
            for (int reg = 0; reg < 4; reg++) {
                int m = mstart + wm * 64 + mt * 16 + rowb + reg;
                if (m >= M) continue;
                float x = v[reg];
                if (MODE == 0) {
                    if (n < D_INNER) bout1[(size_t)m * D_INNER + n] = f2bf(x);
                    else if (n < 2 * D_INNER) bout2[(size_t)m * D_INNER + (n - D_INNER)] = f2bf(silu(x));
                } else if (MODE == 1) {
                    if (n < XPROJ_OUT) fout[(size_t)m * XPROJ_OUT + n] = x;
                } else {
                    if (n < D_MODEL) fout[(size_t)m * D_MODEL + n] = x;
                }
            }
        }
    }
}

// ---------- parallel causal depthwise conv (k=4) + bias + silu ----------
__global__ __launch_bounds__(256) void conv_silu_kernel(
    const ushort_t* __restrict__ xc, const float* __restrict__ w,
    const float* __restrict__ cb, ushort_t* __restrict__ u) {
    int d = blockIdx.x * 256 + threadIdx.x;
    if (d >= D_INNER) return;
    int tok = blockIdx.y;
    int t = tok % SEQ;
    float acc = cb[d];
#pragma unroll
    for (int k = 0; k < 4; k++) {
        int back = 3 - k;
        if (t - back >= 0)
            acc = fmaf(w[d * 4 + k], bf2f(xc[(size_t)(tok - back) * D_INNER + d]), acc);
    }
    u[(size_t)tok * KP_DI + d] = f2bf(silu(acc));
}

// ---------- selective scan: fused dt_proj+softplus, +u*D, *silu(z) --------
// u (bf16, stride KP_DI) is overwritten with y in place.
__global__ __launch_bounds__(64) void scan_kernel(
    ushort_t* __restrict__ u_y, const float* __restrict__ dbl,
    const ushort_t* __restrict__ zs, const float* __restrict__ dt_w,
    const float* __restrict__ dt_b, const float* __restrict__ A_log,
    const float* __restrict__ Dp) {
    int b = blockIdx.y;
    int d = blockIdx.x * 64 + threadIdx.x;
    int lane = threadIdx.x;
    __shared__ float row[XPROJ_OUT];
    bool active = d < D_INNER;
    float A2[D_STATE], h[D_STATE], wdt[DT_RANK];
    float Dd = 0.f, dtb = 0.f;
    if (active) {
#pragma unroll
        for (int n = 0; n < D_STATE; n++) {
            A2[n] = -__expf(A_log[d * D_STATE + n]) * 1.44269504088896341f;
            h[n] = 0.f;
        }
#pragma unroll
        for (int r = 0; r < DT_RANK; r++) wdt[r] = dt_w[d * DT_RANK + r];
        Dd = Dp[d];
        dtb = dt_b[d];
    }
    size_t base_u = (size_t)b * SEQ * KP_DI + d;
    size_t base_z = (size_t)b * SEQ * D_INNER + d;
    size_t dblbase = (size_t)b * SEQ * XPROJ_OUT;
    for (int t = 0; t < SEQ; t++) {
        if (lane < XPROJ_OUT) row[lane] = dbl[dblbase + (size_t)t * XPROJ_OUT + lane];
        __syncthreads();
        if (active) {
            float dtv = dtb;
#pragma unroll
            for (int r = 0; r < DT_RANK; r++) dtv = fmaf(wdt[r], row[r], dtv);
            dtv = fmaxf(dtv, 0.f) + log1pf(__expf(-fabsf(dtv)));
            size_t off_u = base_u + (size_t)t * KP_DI;
            float u_t = bf2f(u_y[off_u]);
            float du = dtv * u_t;
            float acc = 0.f;
#pragma unroll
            for (int n = 0; n < D_STATE; n++) {
                float dA = exp2f(dtv * A2[n]);
                h[n] = fmaf(dA, h[n], du * row[DT_RANK + n]);
                acc = fmaf(h[n], row[DT_RANK + D_STATE + n], acc);
            }
            acc = fmaf(u_t, Dd, acc);
            float zz = bf2f(zs[base_z + (size_t)t * D_INNER]);
            u_y[off_u] = f2bf(acc * zz);
        }
        __syncthreads();
    }
}

// ---------------- classifier + softmax ----------------
__global__ __launch_bounds__(256) void cls_kernel(const float* __restrict__ xf,
                                                  const float* __restrict__ w,
                                                  const float* __restrict__ bias,
                                                  float* __restrict__ out) {
    const int F = SEQ * D_MODEL;  // 56260
    int b = blockIdx.x;
    int tid = threadIdx.x;
    const float* xr = xf + (size_t)b * F;
    float a0 = 0.f, a1 = 0.f, a2 = 0.f;
    for (int j = tid; j < F; j += 256) {
        float v = xr[j];
        a0 = fmaf(v, w[j], a0);
        a1 = fmaf(v, w[F + j], a1);
        a2 = fmaf(v, w[2 * F + j], a2);
    }
    a0 = wave_sum(a0);
    a1 = wave_sum(a1);
    a2 = wave_sum(a2);
    __shared__ float s[3][4];
    int wv = tid >> 6;
    if ((tid & 63) == 0) { s[0][wv] = a0; s[1][wv] = a1; s[2][wv] = a2; }
    __syncthreads();
    if (tid == 0) {
        float l0 = s[0][0] + s[0][1] + s[0][2] + s[0][3] + bias[0];
        float l1 = s[1][0] + s[1][1] + s[1][2] + s[1][3] + bias[1];
        float l2 = s[2][0] + s[2][1] + s[2][2] + s[2][3] + bias[2];
        float mx = fmaxf(l0, fmaxf(l1, l2));
        float e0 = expf(l0 - mx), e1 = expf(l1 - mx), e2 = expf(l2 - mx);
        float inv = 1.f / (e0 + e1 + e2);
        out[b * 3 + 0] = e0 * inv;
        out[b * 3 + 1] = e1 * inv;
        out[b * 3 + 2] = e2 * inv;
    }
}

extern "C" void kernel_launch(void* const* d_in, const int* in_sizes, int n_in,
                              void* d_out, int out_size, void* d_ws, size_t ws_size,
                              hipStream_t stream) {
    const float* x_in   = (const float*)d_in[0];
    const float* ln_g   = (const float*)d_in[1];
    const float* ln_b   = (const float*)d_in[2];
    const float* in_w   = (const float*)d_in[3];
    const float* conv_w = (const float*)d_in[4];
    const float* conv_b = (const float*)d_in[5];
    const float* xp_w   = (const float*)d_in[6];
    const float* dt_w   = (const float*)d_in[7];
    const float* dt_b   = (const float*)d_in[8];
    const float* A_log  = (const float*)d_in[9];
    const float* Dvec   = (const float*)d_in[10];
    const float* out_w  = (const float*)d_in[11];
    const float* cls_w  = (const float*)d_in[12];
    const float* cls_b  = (const float*)d_in[13];
    float* outp = (float*)d_out;

    const size_t WB_IN  = (size_t)N_BLOCKS * NP_IN * KP_IN;    // bf16 elems
    const size_t WB_XP  = (size_t)N_BLOCKS * NP_XP * KP_DI;
    const size_t WB_OUT = (size_t)N_BLOCKS * NP_OUT * KP_DI;
    const size_t wbytes = (WB_IN + WB_XP + WB_OUT) * sizeof(ushort_t);

    // choose batch chunk CB so workspace fits
    int CB = BATCH;
    while (CB > 1) {
        size_t T = (size_t)CB * SEQ;
        size_t need = T * (388 * 4 + KP_IN * 2 + 776 * 2 * 2 + KP_DI * 2 + 57 * 4) + wbytes + 1024;
        if (need <= ws_size) break;
        CB >>= 1;
    }
    const size_t T = (size_t)CB * SEQ;
    const int Mi = (int)T;

    char* p = (char*)d_ws;
    float*    x_cur = (float*)p;          p += T * D_MODEL * sizeof(float);
    ushort_t* x_ln  = (ushort_t*)p;       p += T * KP_IN * sizeof(ushort_t);
    ushort_t* xc    = (ushort_t*)p;       p += T * D_INNER * sizeof(ushort_t);
    ushort_t* zsb   = (ushort_t*)p;       p += T * D_INNER * sizeof(ushort_t);
    ushort_t* ubuf  = (ushort_t*)p;       p += T * KP_DI * sizeof(ushort_t);
    float*    dblb  = (float*)p;          p += T * XPROJ_OUT * sizeof(float);
    ushort_t* w_in  = (ushort_t*)p;       p += WB_IN * sizeof(ushort_t);
    ushort_t* w_xp  = (ushort_t*)p;       p += WB_XP * sizeof(ushort_t);
    ushort_t* w_out = (ushort_t*)p;       p += WB_OUT * sizeof(ushort_t);

    // zero padded activation buffers once (pads stay zero; real cols rewritten)
    hipMemsetAsync(x_ln, 0, T * KP_IN * sizeof(ushort_t), stream);
    hipMemsetAsync(ubuf, 0, T * KP_DI * sizeof(ushort_t), stream);

    // weight conversion (every launch; same work each call)
    padcvt_kernel<<<(int)((WB_IN + 255) / 256), 256, 0, stream>>>(
        in_w, w_in, 2 * D_INNER, D_MODEL, NP_IN, KP_IN, N_BLOCKS);
    padcvt_kernel<<<(int)((WB_XP + 255) / 256), 256, 0, stream>>>(
        xp_w, w_xp, XPROJ_OUT, D_INNER, NP_XP, KP_DI, N_BLOCKS);
    padcvt_kernel<<<(int)((WB_OUT + 255) / 256), 256, 0, stream>>>(
        out_w, w_out, D_MODEL, D_INNER, NP_OUT, KP_DI, N_BLOCKS);

    const int gx = (Mi + 127) / 128;

    for (int c0 = 0; c0 < BATCH; c0 += CB) {
        for (int blk = 0; blk < N_BLOCKS; blk++) {
            const float* xsrc = (blk == 0) ? (x_in + (size_t)c0 * SEQ * D_MODEL) : x_cur;
            // 1. LayerNorm -> x_ln bf16
            ln_kernel<<<Mi, 64, 0, stream>>>(xsrc, ln_g + blk * D_MODEL,
                                             ln_b + blk * D_MODEL, x_ln);
            // 2. in_proj -> xc bf16, zs=silu(z) bf16
            {
                dim3 g(gx, NP_IN / 128);
                mfma_gemm<0><<<g, 256, 0, stream>>>(
                    x_ln, w_in + (size_t)blk * NP_IN * KP_IN, nullptr, xc, zsb, Mi);
            }
            // 3. conv + silu -> ubuf bf16 (parallel over all (tok,d))
            {
                dim3 g((D_INNER + 255) / 256, Mi);
                conv_silu_kernel<<<g, 256, 0, stream>>>(
                    xc, conv_w + (size_t)blk * D_INNER * D_CONV,
                    conv_b + (size_t)blk * D_INNER, ubuf);
            }
            // 4. x_proj -> dbl fp32
            {
                dim3 g(gx, NP_XP / 128);
                mfma_gemm<1><<<g, 256, 0, stream>>>(
                    ubuf, w_xp + (size_t)blk * NP_XP * KP_DI, dblb, nullptr, nullptr, Mi);
            }
            // 5. scan (dt_proj+softplus fused, +u*D, *silu(z)); y over ubuf
            {
                dim3 g((D_INNER + 63) / 64, CB);
                scan_kernel<<<g, 64, 0, stream>>>(
                    ubuf, dblb, zsb,
                    dt_w + (size_t)blk * D_INNER * DT_RANK,
                    dt_b + (size_t)blk * D_INNER,
                    A_log + (size_t)blk * D_INNER * D_STATE,
                    Dvec + (size_t)blk * D_INNER);
            }
            // 6. out_proj -> x_cur fp32
            {
                dim3 g(gx, NP_OUT / 128);
                mfma_gemm<2><<<g, 256, 0, stream>>>(
                    ubuf, w_out + (size_t)blk * NP_OUT * KP_DI, x_cur, nullptr, nullptr, Mi);
            }
        }
        // 7. classifier + softmax
        cls_kernel<<<CB, 256, 0, stream>>>(x_cur, cls_w, cls_b, outp + (size_t)c0 * 3);
    }
}

// Round 4
// 4302.530 us; speedup vs baseline: 3.0287x; 1.1309x over previous
//
#include <hip/hip_runtime.h>
#include <math.h>

#define D_MODEL 388
#define N_BLOCKS 5
#define D_INNER 776
#define D_STATE 16
#define D_CONV 4
#define DT_RANK 25
#define SEQ 145
#define NUM_CLASSES 3
#define BATCH 256
#define XPROJ_OUT (DT_RANK + 2 * D_STATE)  // 57
#define DBL_STRIDE 64                       // padded dbl row: dt@0..24, B@32..47, C@48..63

// padded dims for MFMA (K multiple of 32, N multiple of tile)
#define KP_IN 416     // 388 -> 13*32
#define KP_DI 800     // 776 -> 25*32
#define NP_IN 1664    // 1552 -> 13*128
#define NP_XP 128     // 57 -> 128
#define NP_OUT 512    // 388 -> 4*128

typedef unsigned short ushort_t;
typedef short s16x8 __attribute__((ext_vector_type(8)));
typedef float f32x4 __attribute__((ext_vector_type(4)));

__device__ inline float wave_sum(float v) {
#pragma unroll
    for (int off = 32; off; off >>= 1) v += __shfl_xor(v, off);
    return v;
}
__device__ inline float silu(float x) { return x / (1.f + __expf(-x)); }
__device__ inline ushort_t f2bf(float f) {
    unsigned u = __builtin_bit_cast(unsigned, f);
    u = u + 0x7fffu + ((u >> 16) & 1u);
    return (ushort_t)(u >> 16);
}
__device__ inline float bf2f(ushort_t h) {
    unsigned u = ((unsigned)h) << 16;
    return __builtin_bit_cast(float, u);
}

// ---------- weight pad+convert fp32 -> bf16 (zero-padded) ----------
__global__ __launch_bounds__(256) void padcvt_kernel(const float* __restrict__ src,
                                                     ushort_t* __restrict__ dst,
                                                     int Ns, int Ks, int Np, int Kp,
                                                     int nblk) {
    int idx = blockIdx.x * 256 + threadIdx.x;
    int total = nblk * Np * Kp;
    if (idx >= total) return;
    int k = idx % Kp;
    int rest = idx / Kp;
    int n = rest % Np;
    int blk = rest / Np;
    float v = (n < Ns && k < Ks) ? src[((size_t)blk * Ns + n) * Ks + k] : 0.f;
    dst[idx] = f2bf(v);
}

// ---------- LayerNorm: one wave per token -> bf16 out (stride KP_IN) ------
__global__ __launch_bounds__(64) void ln_kernel(const float* __restrict__ x,
                                                const float* __restrict__ g,
                                                const float* __restrict__ b,
                                                ushort_t* __restrict__ out) {
    int tok = blockIdx.x;
    int lane = threadIdx.x;
    const float* xr = x + (size_t)tok * D_MODEL;
    ushort_t* orow = out + (size_t)tok * KP_IN;
    float vals[7];
    float s = 0.f;
#pragma unroll
    for (int i = 0; i < 7; i++) {
        int idx = lane + i * 64;
        float v = (idx < D_MODEL) ? xr[idx] : 0.f;
        vals[i] = v;
        s += v;
    }
    s = wave_sum(s);
    float mu = s * (1.f / D_MODEL);
    float vs = 0.f;
#pragma unroll
    for (int i = 0; i < 7; i++) {
        int idx = lane + i * 64;
        if (idx < D_MODEL) {
            float d = vals[i] - mu;
            vs += d * d;
        }
    }
    vs = wave_sum(vs);
    float rstd = rsqrtf(vs * (1.f / D_MODEL) + 1e-5f);
#pragma unroll
    for (int i = 0; i < 7; i++) {
        int idx = lane + i * 64;
        if (idx < D_MODEL) orow[idx] = f2bf((vals[i] - mu) * rstd * g[idx] + b[idx]);
    }
}

// ---------- MFMA bf16 GEMM: C[m][n] = sum_k A[m,k] W[n,k] ----------
// MODE 0: in_proj  (KP=416): n<776 -> xc bf16 ; 776<=n<1552 -> zs=silu bf16
// MODE 1: x_proj   (KP=800): n<57  -> dbl fp32 (stride 64, remapped cols)
// MODE 2: out_proj (KP=800): n<388 -> x_cur fp32 (ldc 388)
template <int MODE>
__global__ __launch_bounds__(256) void mfma_gemm(const ushort_t* __restrict__ A,
                                                 const ushort_t* __restrict__ W,
                                                 float* __restrict__ fout,
                                                 ushort_t* __restrict__ bout1,
                                                 ushort_t* __restrict__ bout2,
                                                 int M) {
    constexpr int KP = (MODE == 0) ? KP_IN : KP_DI;
    __shared__ ushort_t As[128 * 40];
    __shared__ ushort_t Ws[128 * 40];
    int tid = threadIdx.x;
    int lane = tid & 63;
    int wave = tid >> 6;
    int wm = wave >> 1, wn = wave & 1;
    int mstart = blockIdx.x * 128;
    int nstart = blockIdx.y * 128;

    f32x4 acc[4][4];
#pragma unroll
    for (int i = 0; i < 4; i++)
#pragma unroll
        for (int j = 0; j < 4; j++) acc[i][j] = {0.f, 0.f, 0.f, 0.f};

    for (int k0 = 0; k0 < KP; k0 += 32) {
#pragma unroll
        for (int i = 0; i < 2; i++) {
            int idx = tid + i * 256;
            int r = idx >> 2;
            int c = (idx & 3) * 8;
            int ra = mstart + r;
            ra = (ra < M) ? ra : (M - 1);
            *(s16x8*)&As[r * 40 + c] = *(const s16x8*)&A[(size_t)ra * KP + k0 + c];
            *(s16x8*)&Ws[r * 40 + c] = *(const s16x8*)&W[(size_t)(nstart + r) * KP + k0 + c];
        }
        __syncthreads();
        s16x8 af[4], bfr[4];
        int koff = (lane >> 4) * 8;
        int rlo = lane & 15;
#pragma unroll
        for (int t = 0; t < 4; t++) {
            af[t] = *(s16x8*)&As[(wm * 64 + t * 16 + rlo) * 40 + koff];
            bfr[t] = *(s16x8*)&Ws[(wn * 64 + t * 16 + rlo) * 40 + koff];
        }
#pragma unroll
        for (int mt = 0; mt < 4; mt++)
#pragma unroll
            for (int nt = 0; nt < 4; nt++)
                acc[mt][nt] = __builtin_amdgcn_mfma_f32_16x16x32_bf16(
                    af[mt], bfr[nt], acc[mt][nt], 0, 0, 0);
        __syncthreads();
    }

    int col = lane & 15;
    int rowb = (lane >> 4) * 4;
#pragma unroll
    for (int mt = 0; mt < 4; mt++) {
#pragma unroll
        for (int nt = 0; nt < 4; nt++) {
            f32x4 v = acc[mt][nt];
            int n = nstart + wn * 64 + nt * 16 + col;
#pragma unroll
            for (int reg = 0; reg < 4; reg++) {
                int m = mstart + wm * 64 + mt * 16 + rowb + reg;
                if (m >= M) continue;
                float x = v[reg];
                if (MODE == 0) {
                    if (n < D_INNER) bout1[(size_t)m * D_INNER + n] = f2bf(x);
                    else if (n < 2 * D_INNER) bout2[(size_t)m * D_INNER + (n - D_INNER)] = f2bf(silu(x));
                } else if (MODE == 1) {
                    if (n < XPROJ_OUT) {
                        int cc = (n < DT_RANK) ? n : (n + 7);  // B->32.., C->48..
                        fout[(size_t)m * DBL_STRIDE + cc] = x;
                    }
                } else {
                    if (n < D_MODEL) fout[(size_t)m * D_MODEL + n] = x;
                }
            }
        }
    }
}

// ---- causal depthwise conv (k=4) + bias + silu: thread per (b,d), roll t ----
__global__ __launch_bounds__(256) void conv_silu_kernel(
    const ushort_t* __restrict__ xc, const float* __restrict__ w,
    const float* __restrict__ cb, ushort_t* __restrict__ u, int nbd) {
    int idx = blockIdx.x * 256 + threadIdx.x;
    if (idx >= nbd) return;
    int b = idx / D_INNER;
    int d = idx - b * D_INNER;
    float w0 = w[d * 4 + 0], w1 = w[d * 4 + 1], w2 = w[d * 4 + 2], w3 = w[d * 4 + 3];
    float bias = cb[d];
    size_t xbase = (size_t)b * SEQ * D_INNER + d;
    size_t ubase = (size_t)b * SEQ * KP_DI + d;
    float x1 = 0.f, x2 = 0.f, x3 = 0.f;
    for (int t = 0; t < SEQ; t++) {
        float x0 = bf2f(xc[xbase + (size_t)t * D_INNER]);
        float acc = bias;
        acc = fmaf(w3, x0, acc);
        acc = fmaf(w2, x1, acc);
        acc = fmaf(w1, x2, acc);
        acc = fmaf(w0, x3, acc);
        u[ubase + (size_t)t * KP_DI] = f2bf(silu(acc));
        x3 = x2; x2 = x1; x1 = x0;
    }
}

// ---------- selective scan: barrier-free, fused dt_proj+softplus ----------
// u (bf16, stride KP_DI) is overwritten with y in place.
__global__ __launch_bounds__(64) void scan_kernel(
    ushort_t* __restrict__ u_y, const float* __restrict__ dbl,
    const ushort_t* __restrict__ zs, const float* __restrict__ dt_w,
    const float* __restrict__ dt_b, const float* __restrict__ A_log,
    const float* __restrict__ Dp) {
    int b = blockIdx.y;
    int d = blockIdx.x * 64 + threadIdx.x;
    bool active = d < D_INNER;
    int dc = active ? d : (D_INNER - 1);
    float A2[D_STATE], h[D_STATE], wdt[DT_RANK];
#pragma unroll
    for (int n = 0; n < D_STATE; n++) {
        A2[n] = -__expf(A_log[dc * D_STATE + n]) * 1.44269504088896341f;
        h[n] = 0.f;
    }
#pragma unroll
    for (int r = 0; r < DT_RANK; r++) wdt[r] = dt_w[dc * DT_RANK + r];
    float Dd = Dp[dc];
    float dtb = dt_b[dc];

    size_t base_u = (size_t)b * SEQ * KP_DI + dc;
    size_t base_z = (size_t)b * SEQ * D_INNER + dc;
    const float* drow = dbl + (size_t)b * SEQ * DBL_STRIDE;

    for (int t = 0; t < SEQ; t++) {
        const f32x4* rp = (const f32x4*)(drow + (size_t)t * DBL_STRIDE);
        f32x4 q0 = rp[0], q1 = rp[1], q2 = rp[2], q3 = rp[3], q4 = rp[4], q5 = rp[5];
        float q24 = drow[(size_t)t * DBL_STRIDE + 24];
        float dtv = dtb;
#pragma unroll
        for (int i = 0; i < 4; i++) {
            dtv = fmaf(wdt[0 + i], q0[i], dtv);
            dtv = fmaf(wdt[4 + i], q1[i], dtv);
            dtv = fmaf(wdt[8 + i], q2[i], dtv);
            dtv = fmaf(wdt[12 + i], q3[i], dtv);
            dtv = fmaf(wdt[16 + i], q4[i], dtv);
            dtv = fmaf(wdt[20 + i], q5[i], dtv);
        }
        dtv = fmaf(wdt[24], q24, dtv);
        dtv = fmaxf(dtv, 0.f) + log1pf(__expf(-fabsf(dtv)));  // softplus
        f32x4 B0 = rp[8], B1 = rp[9], B2 = rp[10], B3 = rp[11];
        f32x4 C0 = rp[12], C1 = rp[13], C2 = rp[14], C3 = rp[15];
        size_t off_u = base_u + (size_t)t * KP_DI;
        float u_t = bf2f(u_y[off_u]);
        float zz = bf2f(zs[base_z + (size_t)t * D_INNER]);
        float du = dtv * u_t;
        float acc = 0.f;
#pragma unroll
        for (int n = 0; n < 4; n++) {
            float dA0 = exp2f(dtv * A2[n]);
            float dA1 = exp2f(dtv * A2[4 + n]);
            float dA2 = exp2f(dtv * A2[8 + n]);
            float dA3 = exp2f(dtv * A2[12 + n]);
            h[n]      = fmaf(dA0, h[n],      du * B0[n]);
            h[4 + n]  = fmaf(dA1, h[4 + n],  du * B1[n]);
            h[8 + n]  = fmaf(dA2, h[8 + n],  du * B2[n]);
            h[12 + n] = fmaf(dA3, h[12 + n], du * B3[n]);
            acc = fmaf(h[n], C0[n], acc);
            acc = fmaf(h[4 + n], C1[n], acc);
            acc = fmaf(h[8 + n], C2[n], acc);
            acc = fmaf(h[12 + n], C3[n], acc);
        }
        acc = fmaf(u_t, Dd, acc);
        if (active) u_y[off_u] = f2bf(acc * silu(zz));
    }
}

// ---------------- classifier + softmax ----------------
__global__ __launch_bounds__(256) void cls_kernel(const float* __restrict__ xf,
                                                  const float* __restrict__ w,
                                                  const float* __restrict__ bias,
                                                  float* __restrict__ out) {
    const int F = SEQ * D_MODEL;  // 56260
    int b = blockIdx.x;
    int tid = threadIdx.x;
    const float* xr = xf + (size_t)b * F;
    float a0 = 0.f, a1 = 0.f, a2 = 0.f;
    for (int j = tid; j < F; j += 256) {
        float v = xr[j];
        a0 = fmaf(v, w[j], a0);
        a1 = fmaf(v, w[F + j], a1);
        a2 = fmaf(v, w[2 * F + j], a2);
    }
    a0 = wave_sum(a0);
    a1 = wave_sum(a1);
    a2 = wave_sum(a2);
    __shared__ float s[3][4];
    int wv = tid >> 6;
    if ((tid & 63) == 0) { s[0][wv] = a0; s[1][wv] = a1; s[2][wv] = a2; }
    __syncthreads();
    if (tid == 0) {
        float l0 = s[0][0] + s[0][1] + s[0][2] + s[0][3] + bias[0];
        float l1 = s[1][0] + s[1][1] + s[1][2] + s[1][3] + bias[1];
        float l2 = s[2][0] + s[2][1] + s[2][2] + s[2][3] + bias[2];
        float mx = fmaxf(l0, fmaxf(l1, l2));
        float e0 = expf(l0 - mx), e1 = expf(l1 - mx), e2 = expf(l2 - mx);
        float inv = 1.f / (e0 + e1 + e2);
        out[b * 3 + 0] = e0 * inv;
        out[b * 3 + 1] = e1 * inv;
        out[b * 3 + 2] = e2 * inv;
    }
}

extern "C" void kernel_launch(void* const* d_in, const int* in_sizes, int n_in,
                              void* d_out, int out_size, void* d_ws, size_t ws_size,
                              hipStream_t stream) {
    const float* x_in   = (const float*)d_in[0];
    const float* ln_g   = (const float*)d_in[1];
    const float* ln_b   = (const float*)d_in[2];
    const float* in_w   = (const float*)d_in[3];
    const float* conv_w = (const float*)d_in[4];
    const float* conv_b = (const float*)d_in[5];
    const float* xp_w   = (const float*)d_in[6];
    const float* dt_w   = (const float*)d_in[7];
    const float* dt_b   = (const float*)d_in[8];
    const float* A_log  = (const float*)d_in[9];
    const float* Dvec   = (const float*)d_in[10];
    const float* out_w  = (const float*)d_in[11];
    const float* cls_w  = (const float*)d_in[12];
    const float* cls_b  = (const float*)d_in[13];
    float* outp = (float*)d_out;

    const size_t WB_IN  = (size_t)N_BLOCKS * NP_IN * KP_IN;    // bf16 elems
    const size_t WB_XP  = (size_t)N_BLOCKS * NP_XP * KP_DI;
    const size_t WB_OUT = (size_t)N_BLOCKS * NP_OUT * KP_DI;
    const size_t wbytes = (WB_IN + WB_XP + WB_OUT) * sizeof(ushort_t);

    // choose batch chunk CB so workspace fits
    int CB = BATCH;
    while (CB > 1) {
        size_t T = (size_t)CB * SEQ;
        size_t need = T * (D_MODEL * 4 + KP_IN * 2 + D_INNER * 2 * 2 + KP_DI * 2 + DBL_STRIDE * 4)
                      + wbytes + 1024;
        if (need <= ws_size) break;
        CB >>= 1;
    }
    const size_t T = (size_t)CB * SEQ;
    const int Mi = (int)T;

    char* p = (char*)d_ws;
    float*    x_cur = (float*)p;          p += T * D_MODEL * sizeof(float);
    ushort_t* x_ln  = (ushort_t*)p;       p += T * KP_IN * sizeof(ushort_t);
    ushort_t* xc    = (ushort_t*)p;       p += T * D_INNER * sizeof(ushort_t);
    ushort_t* zsb   = (ushort_t*)p;       p += T * D_INNER * sizeof(ushort_t);
    ushort_t* ubuf  = (ushort_t*)p;       p += T * KP_DI * sizeof(ushort_t);
    float*    dblb  = (float*)p;          p += T * DBL_STRIDE * sizeof(float);
    ushort_t* w_in  = (ushort_t*)p;       p += WB_IN * sizeof(ushort_t);
    ushort_t* w_xp  = (ushort_t*)p;       p += WB_XP * sizeof(ushort_t);
    ushort_t* w_out = (ushort_t*)p;       p += WB_OUT * sizeof(ushort_t);

    hipMemsetAsync(x_ln, 0, T * KP_IN * sizeof(ushort_t), stream);
    hipMemsetAsync(ubuf, 0, T * KP_DI * sizeof(ushort_t), stream);

    padcvt_kernel<<<(int)((WB_IN + 255) / 256), 256, 0, stream>>>(
        in_w, w_in, 2 * D_INNER, D_MODEL, NP_IN, KP_IN, N_BLOCKS);
    padcvt_kernel<<<(int)((WB_XP + 255) / 256), 256, 0, stream>>>(
        xp_w, w_xp, XPROJ_OUT, D_INNER, NP_XP, KP_DI, N_BLOCKS);
    padcvt_kernel<<<(int)((WB_OUT + 255) / 256), 256, 0, stream>>>(
        out_w, w_out, D_MODEL, D_INNER, NP_OUT, KP_DI, N_BLOCKS);

    const int gx = (Mi + 127) / 128;
    const int nbd = CB * D_INNER;

    for (int c0 = 0; c0 < BATCH; c0 += CB) {
        for (int blk = 0; blk < N_BLOCKS; blk++) {
            const float* xsrc = (blk == 0) ? (x_in + (size_t)c0 * SEQ * D_MODEL) : x_cur;
            ln_kernel<<<Mi, 64, 0, stream>>>(xsrc, ln_g + blk * D_MODEL,
                                             ln_b + blk * D_MODEL, x_ln);
            {
                dim3 g(gx, NP_IN / 128);
                mfma_gemm<0><<<g, 256, 0, stream>>>(
                    x_ln, w_in + (size_t)blk * NP_IN * KP_IN, nullptr, xc, zsb, Mi);
            }
            conv_silu_kernel<<<(nbd + 255) / 256, 256, 0, stream>>>(
                xc, conv_w + (size_t)blk * D_INNER * D_CONV,
                conv_b + (size_t)blk * D_INNER, ubuf, nbd);
            {
                dim3 g(gx, NP_XP / 128);
                mfma_gemm<1><<<g, 256, 0, stream>>>(
                    ubuf, w_xp + (size_t)blk * NP_XP * KP_DI, dblb, nullptr, nullptr, Mi);
            }
            {
                dim3 g((D_INNER + 63) / 64, CB);
                scan_kernel<<<g, 64, 0, stream>>>(
                    ubuf, dblb, zsb,
                    dt_w + (size_t)blk * D_INNER * DT_RANK,
                    dt_b + (size_t)blk * D_INNER,
                    A_log + (size_t)blk * D_INNER * D_STATE,
                    Dvec + (size_t)blk * D_INNER);
            }
            {
                dim3 g(gx, NP_OUT / 128);
                mfma_gemm<2><<<g, 256, 0, stream>>>(
                    ubuf, w_out + (size_t)blk * NP_OUT * KP_DI, x_cur, nullptr, nullptr, Mi);
            }
        }
        cls_kernel<<<CB, 256, 0, stream>>>(x_cur, cls_w, cls_b, outp + (size_t)c0 * 3);
    }
}

// Round 5
// 4238.389 us; speedup vs baseline: 3.0745x; 1.0151x over previous
//
#include <hip/hip_runtime.h>
#include <math.h>

#define D_MODEL 388
#define N_BLOCKS 5
#define D_INNER 776
#define D_STATE 16
#define D_CONV 4
#define DT_RANK 25
#define SEQ 145
#define NUM_CLASSES 3
#define BATCH 256
#define XPROJ_OUT (DT_RANK + 2 * D_STATE)  // 57
#define DBL_STRIDE 32                       // fp32 row: B@0..15, C@16..31

// padded dims for MFMA (K multiple of 32, N multiple of tile)
#define KP_IN 416     // 388 -> 13*32
#define KP_DI 800     // 776 -> 25*32
#define KP_DT 32      // 25 -> 32
#define NP_IN 1664    // 1552 -> 13*128
#define NP_XP 128     // 57 -> 128
#define NP_OUT 512    // 388 -> 4*128
#define NP_DT 896     // 776 -> 7*128

typedef unsigned short ushort_t;
typedef short s16x8 __attribute__((ext_vector_type(8)));
typedef float f32x4 __attribute__((ext_vector_type(4)));

__device__ inline float wave_sum(float v) {
#pragma unroll
    for (int off = 32; off; off >>= 1) v += __shfl_xor(v, off);
    return v;
}
__device__ inline float silu(float x) { return x / (1.f + __expf(-x)); }
__device__ inline ushort_t f2bf(float f) {
    unsigned u = __builtin_bit_cast(unsigned, f);
    u = u + 0x7fffu + ((u >> 16) & 1u);
    return (ushort_t)(u >> 16);
}
__device__ inline float bf2f(ushort_t h) {
    unsigned u = ((unsigned)h) << 16;
    return __builtin_bit_cast(float, u);
}

// ---------- weight pad+convert fp32 -> bf16 (zero-padded) ----------
__global__ __launch_bounds__(256) void padcvt_kernel(const float* __restrict__ src,
                                                     ushort_t* __restrict__ dst,
                                                     int Ns, int Ks, int Np, int Kp,
                                                     int nblk) {
    int idx = blockIdx.x * 256 + threadIdx.x;
    int total = nblk * Np * Kp;
    if (idx >= total) return;
    int k = idx % Kp;
    int rest = idx / Kp;
    int n = rest % Np;
    int blk = rest / Np;
    float v = (n < Ns && k < Ks) ? src[((size_t)blk * Ns + n) * Ks + k] : 0.f;
    dst[idx] = f2bf(v);
}

// ---------- LayerNorm: one wave per token -> bf16 out (stride KP_IN) ------
__global__ __launch_bounds__(64) void ln_kernel(const float* __restrict__ x,
                                                const float* __restrict__ g,
                                                const float* __restrict__ b,
                                                ushort_t* __restrict__ out) {
    int tok = blockIdx.x;
    int lane = threadIdx.x;
    const float* xr = x + (size_t)tok * D_MODEL;
    ushort_t* orow = out + (size_t)tok * KP_IN;
    float vals[7];
    float s = 0.f;
#pragma unroll
    for (int i = 0; i < 7; i++) {
        int idx = lane + i * 64;
        float v = (idx < D_MODEL) ? xr[idx] : 0.f;
        vals[i] = v;
        s += v;
    }
    s = wave_sum(s);
    float mu = s * (1.f / D_MODEL);
    float vs = 0.f;
#pragma unroll
    for (int i = 0; i < 7; i++) {
        int idx = lane + i * 64;
        if (idx < D_MODEL) {
            float d = vals[i] - mu;
            vs += d * d;
        }
    }
    vs = wave_sum(vs);
    float rstd = rsqrtf(vs * (1.f / D_MODEL) + 1e-5f);
#pragma unroll
    for (int i = 0; i < 7; i++) {
        int idx = lane + i * 64;
        if (idx < D_MODEL) orow[idx] = f2bf((vals[i] - mu) * rstd * g[idx] + b[idx]);
    }
}

// ---------- MFMA bf16 GEMM: C[m][n] = sum_k A[m,k] W[n,k] ----------
// MODE 0: in_proj  (KP=416): n<776 -> xc bf16 ; 776<=n<1552 -> zs=silu bf16
// MODE 1: x_proj   (KP=800): n<25 -> dtA bf16 (stride 32); 25<=n<57 -> dbl fp32 (stride 32)
// MODE 2: out_proj (KP=800): n<388 -> x_cur fp32 (ldc 388)
// MODE 3: dt_proj  (KP=32):  n<776 -> dtf fp32 = softplus(x + bias[n]) (ldc 776)
template <int MODE>
__global__ __launch_bounds__(256) void mfma_gemm(const ushort_t* __restrict__ A,
                                                 const ushort_t* __restrict__ W,
                                                 float* __restrict__ fout,
                                                 ushort_t* __restrict__ bout1,
                                                 ushort_t* __restrict__ bout2,
                                                 const float* __restrict__ bias,
                                                 int M) {
    constexpr int KP = (MODE == 0) ? KP_IN : (MODE == 3 ? KP_DT : KP_DI);
    __shared__ ushort_t As[128 * 40];
    __shared__ ushort_t Ws[128 * 40];
    int tid = threadIdx.x;
    int lane = tid & 63;
    int wave = tid >> 6;
    int wm = wave >> 1, wn = wave & 1;
    int mstart = blockIdx.x * 128;
    int nstart = blockIdx.y * 128;

    f32x4 acc[4][4];
#pragma unroll
    for (int i = 0; i < 4; i++)
#pragma unroll
        for (int j = 0; j < 4; j++) acc[i][j] = {0.f, 0.f, 0.f, 0.f};

    for (int k0 = 0; k0 < KP; k0 += 32) {
#pragma unroll
        for (int i = 0; i < 2; i++) {
            int idx = tid + i * 256;
            int r = idx >> 2;
            int c = (idx & 3) * 8;
            int ra = mstart + r;
            ra = (ra < M) ? ra : (M - 1);
            *(s16x8*)&As[r * 40 + c] = *(const s16x8*)&A[(size_t)ra * KP + k0 + c];
            *(s16x8*)&Ws[r * 40 + c] = *(const s16x8*)&W[(size_t)(nstart + r) * KP + k0 + c];
        }
        __syncthreads();
        s16x8 af[4], bfr[4];
        int koff = (lane >> 4) * 8;
        int rlo = lane & 15;
#pragma unroll
        for (int t = 0; t < 4; t++) {
            af[t] = *(s16x8*)&As[(wm * 64 + t * 16 + rlo) * 40 + koff];
            bfr[t] = *(s16x8*)&Ws[(wn * 64 + t * 16 + rlo) * 40 + koff];
        }
#pragma unroll
        for (int mt = 0; mt < 4; mt++)
#pragma unroll
            for (int nt = 0; nt < 4; nt++)
                acc[mt][nt] = __builtin_amdgcn_mfma_f32_16x16x32_bf16(
                    af[mt], bfr[nt], acc[mt][nt], 0, 0, 0);
        __syncthreads();
    }

    int col = lane & 15;
    int rowb = (lane >> 4) * 4;
#pragma unroll
    for (int mt = 0; mt < 4; mt++) {
#pragma unroll
        for (int nt = 0; nt < 4; nt++) {
            f32x4 v = acc[mt][nt];
            int n = nstart + wn * 64 + nt * 16 + col;
#pragma unroll
            for (int reg = 0; reg < 4; reg++) {
                int m = mstart + wm * 64 + mt * 16 + rowb + reg;
                if (m >= M) continue;
                float x = v[reg];
                if (MODE == 0) {
                    if (n < D_INNER) bout1[(size_t)m * D_INNER + n] = f2bf(x);
                    else if (n < 2 * D_INNER) bout2[(size_t)m * D_INNER + (n - D_INNER)] = f2bf(silu(x));
                } else if (MODE == 1) {
                    if (n < DT_RANK) bout1[(size_t)m * KP_DT + n] = f2bf(x);
                    else if (n < XPROJ_OUT) fout[(size_t)m * DBL_STRIDE + (n - DT_RANK)] = x;
                } else if (MODE == 2) {
                    if (n < D_MODEL) fout[(size_t)m * D_MODEL + n] = x;
                } else {  // MODE 3: softplus(x + bias)
                    if (n < D_INNER) {
                        float t2 = x + bias[n];
                        fout[(size_t)m * D_INNER + n] =
                            fmaxf(t2, 0.f) + log1pf(__expf(-fabsf(t2)));
                    }
                }
            }
        }
    }
}

// ---- causal depthwise conv (k=4) + bias + silu: thread per (b,d), roll t ----
__global__ __launch_bounds__(256) void conv_silu_kernel(
    const ushort_t* __restrict__ xc, const float* __restrict__ w,
    const float* __restrict__ cb, ushort_t* __restrict__ u, int nbd) {
    int idx = blockIdx.x * 256 + threadIdx.x;
    if (idx >= nbd) return;
    int b = idx / D_INNER;
    int d = idx - b * D_INNER;
    float w0 = w[d * 4 + 0], w1 = w[d * 4 + 1], w2 = w[d * 4 + 2], w3 = w[d * 4 + 3];
    float bias = cb[d];
    size_t xbase = (size_t)b * SEQ * D_INNER + d;
    size_t ubase = (size_t)b * SEQ * KP_DI + d;
    float x1 = 0.f, x2 = 0.f, x3 = 0.f;
    for (int t = 0; t < SEQ; t++) {
        float x0 = bf2f(xc[xbase + (size_t)t * D_INNER]);
        float acc = bias;
        acc = fmaf(w3, x0, acc);
        acc = fmaf(w2, x1, acc);
        acc = fmaf(w1, x2, acc);
        acc = fmaf(w0, x3, acc);
        u[ubase + (size_t)t * KP_DI] = f2bf(silu(acc));
        x3 = x2; x2 = x1; x1 = x0;
    }
}

// ---------- selective scan: split-state (lane pair per channel) ----------
// lanes 2i,2i+1 share channel d = blk*32+i; half=lane&1 owns states [8h,8h+8).
// u (bf16, stride KP_DI) is overwritten with y in place.
__global__ __launch_bounds__(64) void scan_kernel(
    ushort_t* __restrict__ u_y, const float* __restrict__ dbl,
    const ushort_t* __restrict__ zs, const float* __restrict__ dtf,
    const float* __restrict__ A_log, const float* __restrict__ Dp) {
    int b = blockIdx.y;
    int lane = threadIdx.x;
    int half = lane & 1;
    int d = blockIdx.x * 32 + (lane >> 1);
    bool active = d < D_INNER;
    int dc = active ? d : (D_INNER - 1);

    float A2[8], h[8];
#pragma unroll
    for (int j = 0; j < 8; j++) {
        A2[j] = -__expf(A_log[dc * D_STATE + half * 8 + j]) * 1.44269504088896341f;
        h[j] = 0.f;
    }
    float Dd = Dp[dc];

    int uoff = b * SEQ * KP_DI + dc;
    int zoff = b * SEQ * D_INNER + dc;
    const f32x4* rp = (const f32x4*)(dbl + (size_t)b * SEQ * DBL_STRIDE) + 2 * half;

    for (int t = 0; t < SEQ; t++) {
        f32x4 Bv0 = rp[0];
        f32x4 Bv1 = rp[1];
        f32x4 Cv0 = rp[4 - 2 * half + 2 * half + 4];  // = rp[4] offset already has half
        // note: rp = row + 2*half (f32x4 units). B half at units 0,1 rel; C at +4 units rel.
        f32x4 Cv1 = rp[5];
        float u_t = bf2f(u_y[uoff]);
        float dtv = dtf[zoff];
        float zz = bf2f(zs[zoff]);
        float du = dtv * u_t;
        float acc = 0.f;
#pragma unroll
        for (int j = 0; j < 4; j++) {
            float dA0 = exp2f(dtv * A2[j]);
            float dA1 = exp2f(dtv * A2[4 + j]);
            h[j] = fmaf(dA0, h[j], du * Bv0[j]);
            h[4 + j] = fmaf(dA1, h[4 + j], du * Bv1[j]);
            acc = fmaf(h[j], Cv0[j], acc);
            acc = fmaf(h[4 + j], Cv1[j], acc);
        }
        acc += __shfl_xor(acc, 1);
        float y = fmaf(u_t, Dd, acc) * zz;   // zz is already silu(z)
        if (active && half == 0) u_y[uoff] = f2bf(y);
        uoff += KP_DI;
        zoff += D_INNER;
        rp += 8;
    }
}

// ---------------- classifier + softmax ----------------
__global__ __launch_bounds__(256) void cls_kernel(const float* __restrict__ xf,
                                                  const float* __restrict__ w,
                                                  const float* __restrict__ bias,
                                                  float* __restrict__ out) {
    const int F = SEQ * D_MODEL;  // 56260
    int b = blockIdx.x;
    int tid = threadIdx.x;
    const float* xr = xf + (size_t)b * F;
    float a0 = 0.f, a1 = 0.f, a2 = 0.f;
    for (int j = tid; j < F; j += 256) {
        float v = xr[j];
        a0 = fmaf(v, w[j], a0);
        a1 = fmaf(v, w[F + j], a1);
        a2 = fmaf(v, w[2 * F + j], a2);
    }
    a0 = wave_sum(a0);
    a1 = wave_sum(a1);
    a2 = wave_sum(a2);
    __shared__ float s[3][4];
    int wv = tid >> 6;
    if ((tid & 63) == 0) { s[0][wv] = a0; s[1][wv] = a1; s[2][wv] = a2; }
    __syncthreads();
    if (tid == 0) {
        float l0 = s[0][0] + s[0][1] + s[0][2] + s[0][3] + bias[0];
        float l1 = s[1][0] + s[1][1] + s[1][2] + s[1][3] + bias[1];
        float l2 = s[2][0] + s[2][1] + s[2][2] + s[2][3] + bias[2];
        float mx = fmaxf(l0, fmaxf(l1, l2));
        float e0 = expf(l0 - mx), e1 = expf(l1 - mx), e2 = expf(l2 - mx);
        float inv = 1.f / (e0 + e1 + e2);
        out[b * 3 + 0] = e0 * inv;
        out[b * 3 + 1] = e1 * inv;
        out[b * 3 + 2] = e2 * inv;
    }
}

extern "C" void kernel_launch(void* const* d_in, const int* in_sizes, int n_in,
                              void* d_out, int out_size, void* d_ws, size_t ws_size,
                              hipStream_t stream) {
    const float* x_in   = (const float*)d_in[0];
    const float* ln_g   = (const float*)d_in[1];
    const float* ln_b   = (const float*)d_in[2];
    const float* in_w   = (const float*)d_in[3];
    const float* conv_w = (const float*)d_in[4];
    const float* conv_b = (const float*)d_in[5];
    const float* xp_w   = (const float*)d_in[6];
    const float* dt_w   = (const float*)d_in[7];
    const float* dt_b   = (const float*)d_in[8];
    const float* A_log  = (const float*)d_in[9];
    const float* Dvec   = (const float*)d_in[10];
    const float* out_w  = (const float*)d_in[11];
    const float* cls_w  = (const float*)d_in[12];
    const float* cls_b  = (const float*)d_in[13];
    float* outp = (float*)d_out;

    const size_t WB_IN  = (size_t)N_BLOCKS * NP_IN * KP_IN;    // bf16 elems
    const size_t WB_XP  = (size_t)N_BLOCKS * NP_XP * KP_DI;
    const size_t WB_OUT = (size_t)N_BLOCKS * NP_OUT * KP_DI;
    const size_t WB_DT  = (size_t)N_BLOCKS * NP_DT * KP_DT;
    const size_t wbytes = (WB_IN + WB_XP + WB_OUT + WB_DT) * sizeof(ushort_t);

    // per-token bytes: x_cur + x_ln + xc + zsb + ubuf + dbl + dtA + dtf
    const size_t ptb = D_MODEL * 4 + KP_IN * 2 + D_INNER * 2 + D_INNER * 2 +
                       KP_DI * 2 + DBL_STRIDE * 4 + KP_DT * 2 + D_INNER * 4;
    int CB = BATCH;
    while (CB > 1) {
        size_t need = (size_t)CB * SEQ * ptb + wbytes + 1024;
        if (need <= ws_size) break;
        CB >>= 1;
    }
    const size_t T = (size_t)CB * SEQ;
    const int Mi = (int)T;

    char* p = (char*)d_ws;
    float*    x_cur = (float*)p;          p += T * D_MODEL * sizeof(float);
    ushort_t* x_ln  = (ushort_t*)p;       p += T * KP_IN * sizeof(ushort_t);
    ushort_t* xc    = (ushort_t*)p;       p += T * D_INNER * sizeof(ushort_t);
    ushort_t* zsb   = (ushort_t*)p;       p += T * D_INNER * sizeof(ushort_t);
    ushort_t* ubuf  = (ushort_t*)p;       p += T * KP_DI * sizeof(ushort_t);
    float*    dblb  = (float*)p;          p += T * DBL_STRIDE * sizeof(float);
    ushort_t* dtA   = (ushort_t*)p;       p += T * KP_DT * sizeof(ushort_t);
    float*    dtf   = (float*)p;          p += T * D_INNER * sizeof(float);
    ushort_t* w_in  = (ushort_t*)p;       p += WB_IN * sizeof(ushort_t);
    ushort_t* w_xp  = (ushort_t*)p;       p += WB_XP * sizeof(ushort_t);
    ushort_t* w_out = (ushort_t*)p;       p += WB_OUT * sizeof(ushort_t);
    ushort_t* w_dt  = (ushort_t*)p;       p += WB_DT * sizeof(ushort_t);

    hipMemsetAsync(x_ln, 0, T * KP_IN * sizeof(ushort_t), stream);
    hipMemsetAsync(ubuf, 0, T * KP_DI * sizeof(ushort_t), stream);

    padcvt_kernel<<<(int)((WB_IN + 255) / 256), 256, 0, stream>>>(
        in_w, w_in, 2 * D_INNER, D_MODEL, NP_IN, KP_IN, N_BLOCKS);
    padcvt_kernel<<<(int)((WB_XP + 255) / 256), 256, 0, stream>>>(
        xp_w, w_xp, XPROJ_OUT, D_INNER, NP_XP, KP_DI, N_BLOCKS);
    padcvt_kernel<<<(int)((WB_OUT + 255) / 256), 256, 0, stream>>>(
        out_w, w_out, D_MODEL, D_INNER, NP_OUT, KP_DI, N_BLOCKS);
    padcvt_kernel<<<(int)((WB_DT + 255) / 256), 256, 0, stream>>>(
        dt_w, w_dt, D_INNER, DT_RANK, NP_DT, KP_DT, N_BLOCKS);

    const int gx = (Mi + 127) / 128;
    const int nbd = CB * D_INNER;

    for (int c0 = 0; c0 < BATCH; c0 += CB) {
        for (int blk = 0; blk < N_BLOCKS; blk++) {
            const float* xsrc = (blk == 0) ? (x_in + (size_t)c0 * SEQ * D_MODEL) : x_cur;
            ln_kernel<<<Mi, 64, 0, stream>>>(xsrc, ln_g + blk * D_MODEL,
                                             ln_b + blk * D_MODEL, x_ln);
            {   // in_proj -> xc bf16, zs=silu(z) bf16
                dim3 g(gx, NP_IN / 128);
                mfma_gemm<0><<<g, 256, 0, stream>>>(
                    x_ln, w_in + (size_t)blk * NP_IN * KP_IN, nullptr, xc, zsb, nullptr, Mi);
            }
            conv_silu_kernel<<<(nbd + 255) / 256, 256, 0, stream>>>(
                xc, conv_w + (size_t)blk * D_INNER * D_CONV,
                conv_b + (size_t)blk * D_INNER, ubuf, nbd);
            {   // x_proj -> dtA bf16 + dbl fp32 (B/C)
                dim3 g(gx, NP_XP / 128);
                mfma_gemm<1><<<g, 256, 0, stream>>>(
                    ubuf, w_xp + (size_t)blk * NP_XP * KP_DI, dblb, dtA, nullptr, nullptr, Mi);
            }
            {   // dt_proj + softplus -> dtf fp32
                dim3 g(gx, NP_DT / 128);
                mfma_gemm<3><<<g, 256, 0, stream>>>(
                    dtA, w_dt + (size_t)blk * NP_DT * KP_DT, dtf, nullptr, nullptr,
                    dt_b + (size_t)blk * D_INNER, Mi);
            }
            {   // scan; y over ubuf
                dim3 g((D_INNER + 31) / 32, CB);
                scan_kernel<<<g, 64, 0, stream>>>(
                    ubuf, dblb, zsb, dtf,
                    A_log + (size_t)blk * D_INNER * D_STATE,
                    Dvec + (size_t)blk * D_INNER);
            }
            {   // out_proj -> x_cur fp32
                dim3 g(gx, NP_OUT / 128);
                mfma_gemm<2><<<g, 256, 0, stream>>>(
                    ubuf, w_out + (size_t)blk * NP_OUT * KP_DI, x_cur, nullptr, nullptr, nullptr, Mi);
            }
        }
        cls_kernel<<<CB, 256, 0, stream>>>(x_cur, cls_w, cls_b, outp + (size_t)c0 * 3);
    }
}

// Round 6
// 4041.656 us; speedup vs baseline: 3.2241x; 1.0487x over previous
//
#include <hip/hip_runtime.h>
#include <math.h>

#define D_MODEL 388
#define N_BLOCKS 5
#define D_INNER 776
#define D_STATE 16
#define D_CONV 4
#define DT_RANK 25
#define SEQ 145
#define NUM_CLASSES 3
#define BATCH 256
#define XPROJ_OUT (DT_RANK + 2 * D_STATE)  // 57
#define DBL_STRIDE 32                       // fp32 row: B@0..15, C@16..31

// padded dims for MFMA (K multiple of 32, N multiple of tile)
#define KP_IN 416     // 388 -> 13*32
#define KP_DI 800     // 776 -> 25*32
#define KP_DT 32      // 25 -> 32
#define NP_IN 1664    // 1552 -> 13*128
#define NP_XP 128     // 57 -> 128
#define NP_OUT 512    // 388 -> 4*128
#define NP_DT 896     // 776 -> 7*128

typedef unsigned short ushort_t;
typedef short s16x8 __attribute__((ext_vector_type(8)));
typedef float f32x4 __attribute__((ext_vector_type(4)));

__device__ inline float wave_sum(float v) {
#pragma unroll
    for (int off = 32; off; off >>= 1) v += __shfl_xor(v, off);
    return v;
}
__device__ inline float silu(float x) { return x / (1.f + __expf(-x)); }
__device__ inline ushort_t f2bf(float f) {
    unsigned u = __builtin_bit_cast(unsigned, f);
    u = u + 0x7fffu + ((u >> 16) & 1u);
    return (ushort_t)(u >> 16);
}
__device__ inline float bf2f(ushort_t h) {
    unsigned u = ((unsigned)h) << 16;
    return __builtin_bit_cast(float, u);
}

// ---------- weight pad+convert fp32 -> bf16 (zero-padded) ----------
__global__ __launch_bounds__(256) void padcvt_kernel(const float* __restrict__ src,
                                                     ushort_t* __restrict__ dst,
                                                     int Ns, int Ks, int Np, int Kp,
                                                     int nblk) {
    int idx = blockIdx.x * 256 + threadIdx.x;
    int total = nblk * Np * Kp;
    if (idx >= total) return;
    int k = idx % Kp;
    int rest = idx / Kp;
    int n = rest % Np;
    int blk = rest / Np;
    float v = (n < Ns && k < Ks) ? src[((size_t)blk * Ns + n) * Ks + k] : 0.f;
    dst[idx] = f2bf(v);
}

// ---------- LayerNorm: one wave per token -> bf16 out (stride KP_IN) ------
__global__ __launch_bounds__(64) void ln_kernel(const float* __restrict__ x,
                                                const float* __restrict__ g,
                                                const float* __restrict__ b,
                                                ushort_t* __restrict__ out) {
    int tok = blockIdx.x;
    int lane = threadIdx.x;
    const float* xr = x + (size_t)tok * D_MODEL;
    ushort_t* orow = out + (size_t)tok * KP_IN;
    float vals[7];
    float s = 0.f;
#pragma unroll
    for (int i = 0; i < 7; i++) {
        int idx = lane + i * 64;
        float v = (idx < D_MODEL) ? xr[idx] : 0.f;
        vals[i] = v;
        s += v;
    }
    s = wave_sum(s);
    float mu = s * (1.f / D_MODEL);
    float vs = 0.f;
#pragma unroll
    for (int i = 0; i < 7; i++) {
        int idx = lane + i * 64;
        if (idx < D_MODEL) {
            float d = vals[i] - mu;
            vs += d * d;
        }
    }
    vs = wave_sum(vs);
    float rstd = rsqrtf(vs * (1.f / D_MODEL) + 1e-5f);
#pragma unroll
    for (int i = 0; i < 7; i++) {
        int idx = lane + i * 64;
        if (idx < D_MODEL) orow[idx] = f2bf((vals[i] - mu) * rstd * g[idx] + b[idx]);
    }
}

// ---------- MFMA bf16 GEMM with global_load_lds staging ----------
// C[m][n] = sum_k A[m,k] W[n,k]
// MODE 0: in_proj  (KP=416): n<776 -> xc bf16 ; 776<=n<1552 -> zs=silu bf16
// MODE 1: x_proj   (KP=800): n<25 -> dtA bf16 (stride 32); 25<=n<57 -> dbl fp32 (stride 32)
// MODE 2: out_proj (KP=800): n<388 -> x_cur fp32 (ldc 388)
// MODE 3: dt_proj  (KP=32):  n<776 -> dtf fp32 = softplus(x + bias[n]) (ldc 776)
template <int MODE>
__global__ __launch_bounds__(256) void mfma_gemm(const ushort_t* __restrict__ A,
                                                 const ushort_t* __restrict__ W,
                                                 float* __restrict__ fout,
                                                 ushort_t* __restrict__ bout1,
                                                 ushort_t* __restrict__ bout2,
                                                 const float* __restrict__ bias,
                                                 int M) {
    constexpr int KP = (MODE == 0) ? KP_IN : (MODE == 3 ? KP_DT : KP_DI);
    __shared__ ushort_t As[128 * 32];   // unpadded: global_load_lds needs linear lane dest
    __shared__ ushort_t Ws[128 * 32];
    int tid = threadIdx.x;
    int lane = tid & 63;
    int wave = tid >> 6;
    int wm = wave >> 1, wn = wave & 1;
    int mstart = blockIdx.x * 128;
    int nstart = blockIdx.y * 128;

    f32x4 acc[4][4];
#pragma unroll
    for (int i = 0; i < 4; i++)
#pragma unroll
        for (int j = 0; j < 4; j++) acc[i][j] = {0.f, 0.f, 0.f, 0.f};

    for (int k0 = 0; k0 < KP; k0 += 32) {
        // stage 128x32 ushort tiles: slot idx = (wave*2+s)*64+lane, 16 B each
#pragma unroll
        for (int s = 0; s < 2; s++) {
            int idx = (wave * 2 + s) * 64 + lane;
            int row = idx >> 2;
            int ch = idx & 3;           // 16-B chunk within the 64-B row
            int ra = mstart + row;
            ra = (ra < M) ? ra : (M - 1);
            const ushort_t* ga = A + (size_t)ra * KP + k0 + ch * 8;
            const ushort_t* gw = W + (size_t)(nstart + row) * KP + k0 + ch * 8;
            __builtin_amdgcn_global_load_lds(
                (const __attribute__((address_space(1))) unsigned int*)ga,
                (__attribute__((address_space(3))) unsigned int*)&As[(size_t)(wave * 2 + s) * 64 * 8],
                16, 0, 0);
            __builtin_amdgcn_global_load_lds(
                (const __attribute__((address_space(1))) unsigned int*)gw,
                (__attribute__((address_space(3))) unsigned int*)&Ws[(size_t)(wave * 2 + s) * 64 * 8],
                16, 0, 0);
        }
        __syncthreads();
        s16x8 af[4], bfr[4];
        int koff = (lane >> 4) * 8;
        int rlo = lane & 15;
#pragma unroll
        for (int t = 0; t < 4; t++) {
            af[t] = *(s16x8*)&As[(wm * 64 + t * 16 + rlo) * 32 + koff];
            bfr[t] = *(s16x8*)&Ws[(wn * 64 + t * 16 + rlo) * 32 + koff];
        }
#pragma unroll
        for (int mt = 0; mt < 4; mt++)
#pragma unroll
            for (int nt = 0; nt < 4; nt++)
                acc[mt][nt] = __builtin_amdgcn_mfma_f32_16x16x32_bf16(
                    af[mt], bfr[nt], acc[mt][nt], 0, 0, 0);
        __syncthreads();
    }

    int col = lane & 15;
    int rowb = (lane >> 4) * 4;
#pragma unroll
    for (int mt = 0; mt < 4; mt++) {
#pragma unroll
        for (int nt = 0; nt < 4; nt++) {
            f32x4 v = acc[mt][nt];
            int n = nstart + wn * 64 + nt * 16 + col;
#pragma unroll
            for (int reg = 0; reg < 4; reg++) {
                int m = mstart + wm * 64 + mt * 16 + rowb + reg;
                if (m >= M) continue;
                float x = v[reg];
                if (MODE == 0) {
                    if (n < D_INNER) bout1[(size_t)m * D_INNER + n] = f2bf(x);
                    else if (n < 2 * D_INNER) bout2[(size_t)m * D_INNER + (n - D_INNER)] = f2bf(silu(x));
                } else if (MODE == 1) {
                    if (n < DT_RANK) bout1[(size_t)m * KP_DT + n] = f2bf(x);
                    else if (n < XPROJ_OUT) fout[(size_t)m * DBL_STRIDE + (n - DT_RANK)] = x;
                } else if (MODE == 2) {
                    if (n < D_MODEL) fout[(size_t)m * D_MODEL + n] = x;
                } else {  // MODE 3: softplus(x + bias)
                    if (n < D_INNER) {
                        float t2 = x + bias[n];
                        fout[(size_t)m * D_INNER + n] =
                            fmaxf(t2, 0.f) + log1pf(__expf(-fabsf(t2)));
                    }
                }
            }
        }
    }
}

// ---- causal depthwise conv (k=4) + bias + silu: thread per (b,d), roll t ----
__global__ __launch_bounds__(256) void conv_silu_kernel(
    const ushort_t* __restrict__ xc, const float* __restrict__ w,
    const float* __restrict__ cb, ushort_t* __restrict__ u, int nbd) {
    int idx = blockIdx.x * 256 + threadIdx.x;
    if (idx >= nbd) return;
    int b = idx / D_INNER;
    int d = idx - b * D_INNER;
    float w0 = w[d * 4 + 0], w1 = w[d * 4 + 1], w2 = w[d * 4 + 2], w3 = w[d * 4 + 3];
    float bias = cb[d];
    size_t xbase = (size_t)b * SEQ * D_INNER + d;
    size_t ubase = (size_t)b * SEQ * KP_DI + d;
    float x1 = 0.f, x2 = 0.f, x3 = 0.f;
    for (int t = 0; t < SEQ; t++) {
        float x0 = bf2f(xc[xbase + (size_t)t * D_INNER]);
        float acc = bias;
        acc = fmaf(w3, x0, acc);
        acc = fmaf(w2, x1, acc);
        acc = fmaf(w1, x2, acc);
        acc = fmaf(w0, x3, acc);
        u[ubase + (size_t)t * KP_DI] = f2bf(silu(acc));
        x3 = x2; x2 = x1; x1 = x0;
    }
}

// ---------- selective scan: quarter-state (4 lanes per channel) ----------
// lanes 4i..4i+3 share channel d; sub=lane&3 owns states [4*sub, 4*sub+4).
// dbl row = 8 f32x4: B chunks rp[0..3], C chunks rp[4..7] -> lane reads rp[sub], rp[4+sub].
// u (bf16, stride KP_DI) is overwritten with y in place.
__global__ __launch_bounds__(256) void scan_kernel(
    ushort_t* __restrict__ u_y, const float* __restrict__ dbl,
    const ushort_t* __restrict__ zs, const float* __restrict__ dtf,
    const float* __restrict__ A_log, const float* __restrict__ Dp) {
    int b = blockIdx.y;
    int tid = threadIdx.x;
    int sub = tid & 3;
    int d = blockIdx.x * 64 + (tid >> 2);
    bool active = d < D_INNER;
    int dc = active ? d : (D_INNER - 1);

    float A2[4], h[4];
#pragma unroll
    for (int j = 0; j < 4; j++) {
        A2[j] = -__expf(A_log[dc * D_STATE + sub * 4 + j]) * 1.44269504088896341f;
        h[j] = 0.f;
    }
    float Dd = Dp[dc];

    int uoff = b * SEQ * KP_DI + dc;
    int zoff = b * SEQ * D_INNER + dc;
    const f32x4* rp = (const f32x4*)(dbl + (size_t)b * SEQ * DBL_STRIDE);

    for (int t = 0; t < SEQ; t++) {
        f32x4 Bv = rp[sub];
        f32x4 Cv = rp[4 + sub];
        float u_t = bf2f(u_y[uoff]);
        float dtv = dtf[zoff];
        float zz = bf2f(zs[zoff]);
        float du = dtv * u_t;
        float acc = 0.f;
#pragma unroll
        for (int j = 0; j < 4; j++) {
            float dA = exp2f(dtv * A2[j]);
            h[j] = fmaf(dA, h[j], du * Bv[j]);
            acc = fmaf(h[j], Cv[j], acc);
        }
        acc += __shfl_xor(acc, 1);
        acc += __shfl_xor(acc, 2);
        float y = fmaf(u_t, Dd, acc) * zz;   // zz is already silu(z)
        if (active && sub == 0) u_y[uoff] = f2bf(y);
        uoff += KP_DI;
        zoff += D_INNER;
        rp += 8;
    }
}

// ---------------- classifier + softmax ----------------
__global__ __launch_bounds__(256) void cls_kernel(const float* __restrict__ xf,
                                                  const float* __restrict__ w,
                                                  const float* __restrict__ bias,
                                                  float* __restrict__ out) {
    const int F = SEQ * D_MODEL;  // 56260
    int b = blockIdx.x;
    int tid = threadIdx.x;
    const float* xr = xf + (size_t)b * F;
    float a0 = 0.f, a1 = 0.f, a2 = 0.f;
    for (int j = tid; j < F; j += 256) {
        float v = xr[j];
        a0 = fmaf(v, w[j], a0);
        a1 = fmaf(v, w[F + j], a1);
        a2 = fmaf(v, w[2 * F + j], a2);
    }
    a0 = wave_sum(a0);
    a1 = wave_sum(a1);
    a2 = wave_sum(a2);
    __shared__ float s[3][4];
    int wv = tid >> 6;
    if ((tid & 63) == 0) { s[0][wv] = a0; s[1][wv] = a1; s[2][wv] = a2; }
    __syncthreads();
    if (tid == 0) {
        float l0 = s[0][0] + s[0][1] + s[0][2] + s[0][3] + bias[0];
        float l1 = s[1][0] + s[1][1] + s[1][2] + s[1][3] + bias[1];
        float l2 = s[2][0] + s[2][1] + s[2][2] + s[2][3] + bias[2];
        float mx = fmaxf(l0, fmaxf(l1, l2));
        float e0 = expf(l0 - mx), e1 = expf(l1 - mx), e2 = expf(l2 - mx);
        float inv = 1.f / (e0 + e1 + e2);
        out[b * 3 + 0] = e0 * inv;
        out[b * 3 + 1] = e1 * inv;
        out[b * 3 + 2] = e2 * inv;
    }
}

extern "C" void kernel_launch(void* const* d_in, const int* in_sizes, int n_in,
                              void* d_out, int out_size, void* d_ws, size_t ws_size,
                              hipStream_t stream) {
    const float* x_in   = (const float*)d_in[0];
    const float* ln_g   = (const float*)d_in[1];
    const float* ln_b   = (const float*)d_in[2];
    const float* in_w   = (const float*)d_in[3];
    const float* conv_w = (const float*)d_in[4];
    const float* conv_b = (const float*)d_in[5];
    const float* xp_w   = (const float*)d_in[6];
    const float* dt_w   = (const float*)d_in[7];
    const float* dt_b   = (const float*)d_in[8];
    const float* A_log  = (const float*)d_in[9];
    const float* Dvec   = (const float*)d_in[10];
    const float* out_w  = (const float*)d_in[11];
    const float* cls_w  = (const float*)d_in[12];
    const float* cls_b  = (const float*)d_in[13];
    float* outp = (float*)d_out;

    const size_t WB_IN  = (size_t)N_BLOCKS * NP_IN * KP_IN;    // bf16 elems
    const size_t WB_XP  = (size_t)N_BLOCKS * NP_XP * KP_DI;
    const size_t WB_OUT = (size_t)N_BLOCKS * NP_OUT * KP_DI;
    const size_t WB_DT  = (size_t)N_BLOCKS * NP_DT * KP_DT;
    const size_t wbytes = (WB_IN + WB_XP + WB_OUT + WB_DT) * sizeof(ushort_t);

    // per-token bytes: x_cur + x_ln + xc + zsb + ubuf + dbl + dtA + dtf
    const size_t ptb = D_MODEL * 4 + KP_IN * 2 + D_INNER * 2 + D_INNER * 2 +
                       KP_DI * 2 + DBL_STRIDE * 4 + KP_DT * 2 + D_INNER * 4;
    int CB = BATCH;
    while (CB > 1) {
        size_t need = (size_t)CB * SEQ * ptb + wbytes + 1024;
        if (need <= ws_size) break;
        CB >>= 1;
    }
    const size_t T = (size_t)CB * SEQ;
    const int Mi = (int)T;

    char* p = (char*)d_ws;
    float*    x_cur = (float*)p;          p += T * D_MODEL * sizeof(float);
    ushort_t* x_ln  = (ushort_t*)p;       p += T * KP_IN * sizeof(ushort_t);
    ushort_t* xc    = (ushort_t*)p;       p += T * D_INNER * sizeof(ushort_t);
    ushort_t* zsb   = (ushort_t*)p;       p += T * D_INNER * sizeof(ushort_t);
    ushort_t* ubuf  = (ushort_t*)p;       p += T * KP_DI * sizeof(ushort_t);
    float*    dblb  = (float*)p;          p += T * DBL_STRIDE * sizeof(float);
    ushort_t* dtA   = (ushort_t*)p;       p += T * KP_DT * sizeof(ushort_t);
    float*    dtf   = (float*)p;          p += T * D_INNER * sizeof(float);
    ushort_t* w_in  = (ushort_t*)p;       p += WB_IN * sizeof(ushort_t);
    ushort_t* w_xp  = (ushort_t*)p;       p += WB_XP * sizeof(ushort_t);
    ushort_t* w_out = (ushort_t*)p;       p += WB_OUT * sizeof(ushort_t);
    ushort_t* w_dt  = (ushort_t*)p;       p += WB_DT * sizeof(ushort_t);

    hipMemsetAsync(x_ln, 0, T * KP_IN * sizeof(ushort_t), stream);
    hipMemsetAsync(ubuf, 0, T * KP_DI * sizeof(ushort_t), stream);

    padcvt_kernel<<<(int)((WB_IN + 255) / 256), 256, 0, stream>>>(
        in_w, w_in, 2 * D_INNER, D_MODEL, NP_IN, KP_IN, N_BLOCKS);
    padcvt_kernel<<<(int)((WB_XP + 255) / 256), 256, 0, stream>>>(
        xp_w, w_xp, XPROJ_OUT, D_INNER, NP_XP, KP_DI, N_BLOCKS);
    padcvt_kernel<<<(int)((WB_OUT + 255) / 256), 256, 0, stream>>>(
        out_w, w_out, D_MODEL, D_INNER, NP_OUT, KP_DI, N_BLOCKS);
    padcvt_kernel<<<(int)((WB_DT + 255) / 256), 256, 0, stream>>>(
        dt_w, w_dt, D_INNER, DT_RANK, NP_DT, KP_DT, N_BLOCKS);

    const int gx = (Mi + 127) / 128;
    const int nbd = CB * D_INNER;

    for (int c0 = 0; c0 < BATCH; c0 += CB) {
        for (int blk = 0; blk < N_BLOCKS; blk++) {
            const float* xsrc = (blk == 0) ? (x_in + (size_t)c0 * SEQ * D_MODEL) : x_cur;
            ln_kernel<<<Mi, 64, 0, stream>>>(xsrc, ln_g + blk * D_MODEL,
                                             ln_b + blk * D_MODEL, x_ln);
            {   // in_proj -> xc bf16, zs=silu(z) bf16
                dim3 g(gx, NP_IN / 128);
                mfma_gemm<0><<<g, 256, 0, stream>>>(
                    x_ln, w_in + (size_t)blk * NP_IN * KP_IN, nullptr, xc, zsb, nullptr, Mi);
            }
            conv_silu_kernel<<<(nbd + 255) / 256, 256, 0, stream>>>(
                xc, conv_w + (size_t)blk * D_INNER * D_CONV,
                conv_b + (size_t)blk * D_INNER, ubuf, nbd);
            {   // x_proj -> dtA bf16 + dbl fp32 (B/C)
                dim3 g(gx, NP_XP / 128);
                mfma_gemm<1><<<g, 256, 0, stream>>>(
                    ubuf, w_xp + (size_t)blk * NP_XP * KP_DI, dblb, dtA, nullptr, nullptr, Mi);
            }
            {   // dt_proj + softplus -> dtf fp32
                dim3 g(gx, NP_DT / 128);
                mfma_gemm<3><<<g, 256, 0, stream>>>(
                    dtA, w_dt + (size_t)blk * NP_DT * KP_DT, dtf, nullptr, nullptr,
                    dt_b + (size_t)blk * D_INNER, Mi);
            }
            {   // scan; y over ubuf
                dim3 g((D_INNER + 63) / 64, CB);
                scan_kernel<<<g, 256, 0, stream>>>(
                    ubuf, dblb, zsb, dtf,
                    A_log + (size_t)blk * D_INNER * D_STATE,
                    Dvec + (size_t)blk * D_INNER);
            }
            {   // out_proj -> x_cur fp32
                dim3 g(gx, NP_OUT / 128);
                mfma_gemm<2><<<g, 256, 0, stream>>>(
                    ubuf, w_out + (size_t)blk * NP_OUT * KP_DI, x_cur, nullptr, nullptr, nullptr, Mi);
            }
        }
        cls_kernel<<<CB, 256, 0, stream>>>(x_cur, cls_w, cls_b, outp + (size_t)c0 * 3);
    }
}